// Round 1
// baseline (339.535 us; speedup 1.0000x reference)
//
#include <hip/hip_runtime.h>
#include <math.h>

// ForceMatchingLoss fused kernel (fp32, one block per batch).
// agg_jac[d][e] = scale*( sum_s w_s v_s[d] k_s[e] - sum_q out_q[d] kbar_q[e] )
// with w_s = sum_q p_qs  (clip commutes: reference clips AFTER summing over q).

namespace {
constexpr int Bn = 256, Qn = 16, Sn = 512, Mn = 8, Dn = 128;
constexpr int TS = 16;   // s-tile rows staged to LDS
constexpr int NT = 256;  // threads per block
constexpr float SCALE = 0.08838834764831845f;  // 1/sqrt(128)
constexpr float CLIPV = 50.0f;

__global__ void zero_kernel(float* out) {
  if (threadIdx.x == 0) out[0] = 0.0f;
}

__global__ __launch_bounds__(NT) void fm_kernel(
    const float* __restrict__ Qg, const float* __restrict__ Kg,
    const float* __restrict__ Vg, const float* __restrict__ Kcg,
    const float* __restrict__ Vcg, float* __restrict__ out) {
  const int b = blockIdx.x;
  const int t = threadIdx.x;
  const int lane = t & 63;
  const int wave = t >> 6;

  __shared__ __align__(16) float qs[Qn][Dn];          // 8 KB
  __shared__ __align__(16) float pbuf[Qn][Sn + 1];    // 32.8 KB (scores/probs; later out/kbar overlay)
  __shared__ __align__(16) float kt[TS][Dn + 4];      // 8.25 KB
  __shared__ __align__(16) float vt[TS][Dn + 4];      // 8.25 KB
  __shared__ float wsum[Sn];                          // 2 KB
  __shared__ float pcg[Qn][Mn];
  __shared__ float wcg[Mn];
  __shared__ float red[4][4];

  const float* Qb = Qg + (size_t)b * Qn * Dn;
  const float* Kb = Kg + (size_t)b * Sn * Dn;
  const float* Vb = Vg + (size_t)b * Sn * Dn;
  const float* Kc = Kcg + (size_t)b * Mn * Dn;
  const float* Vc = Vcg + (size_t)b * Mn * Dn;

  // ---- load Q tile (2048 floats = 512 float4) ----
  {
    const float4* src = (const float4*)Qb;
    float4* dst = (float4*)&qs[0][0];
    dst[t] = src[t];
    dst[t + NT] = src[t + NT];
  }

  // ---- Phase 1: scores -> pbuf (scaled) ----
  const int q1 = t >> 4;  // 0..15
  const int s1 = t & 15;  // 0..15
  for (int st = 0; st < Sn / TS; ++st) {
    __syncthreads();
    const float4* ksrc = (const float4*)(Kb + st * TS * Dn);
    for (int g = t; g < TS * Dn / 4; g += NT) {
      int row = (g * 4) / Dn, col = (g * 4) % Dn;
      *(float4*)&kt[row][col] = ksrc[g];
    }
    __syncthreads();
    float acc = 0.f;
    const float4* qrow = (const float4*)&qs[q1][0];
    const float4* krow = (const float4*)&kt[s1][0];
#pragma unroll
    for (int kk = 0; kk < Dn / 4; ++kk) {
      float4 a = qrow[kk], c = krow[kk];
      acc += a.x * c.x + a.y * c.y + a.z * c.z + a.w * c.w;
    }
    pbuf[q1][st * TS + s1] = acc * SCALE;
  }
  __syncthreads();

  // ---- Phase 2: softmax rows (4 waves x 4 rows each) + column sums ----
  for (int q = wave; q < Qn; q += 4) {
    float m = -1e30f;
    for (int j = lane; j < Sn; j += 64) m = fmaxf(m, pbuf[q][j]);
#pragma unroll
    for (int o = 32; o; o >>= 1) m = fmaxf(m, __shfl_xor(m, o));
    float sum = 0.f;
    for (int j = lane; j < Sn; j += 64) {
      float e = expf(pbuf[q][j] - m);
      pbuf[q][j] = e;
      sum += e;
    }
#pragma unroll
    for (int o = 32; o; o >>= 1) sum += __shfl_xor(sum, o);
    float inv = 1.f / sum;
    for (int j = lane; j < Sn; j += 64) pbuf[q][j] *= inv;
  }
  __syncthreads();
  for (int s = t; s < Sn; s += NT) {
    float w = 0.f;
#pragma unroll
    for (int q = 0; q < Qn; ++q) w += pbuf[q][s];
    wsum[s] = w;
  }

  // ---- Phase 3+4 fused: out/kbar (regs) + C = sum_s wv k^T (8x8 reg tile) ----
  const int qo = t & 15;        // owned q for out/kbar; col-group for C
  const int dg = t >> 4;        // row-group
  const int d0 = dg * 8;        // rows of C; dims of out/kbar
  const int e0 = qo * 8;        // cols of C

  float outa[8], kba[8], C[8][8];
#pragma unroll
  for (int i = 0; i < 8; ++i) {
    outa[i] = 0.f;
    kba[i] = 0.f;
#pragma unroll
    for (int j = 0; j < 8; ++j) C[i][j] = 0.f;
  }

  for (int st = 0; st < Sn / TS; ++st) {
    __syncthreads();
    const float4* ksrc = (const float4*)(Kb + st * TS * Dn);
    const float4* vsrc = (const float4*)(Vb + st * TS * Dn);
    for (int g = t; g < TS * Dn / 4; g += NT) {
      int row = (g * 4) / Dn, col = (g * 4) % Dn;
      *(float4*)&kt[row][col] = ksrc[g];
      *(float4*)&vt[row][col] = vsrc[g];
    }
    __syncthreads();
#pragma unroll
    for (int sl = 0; sl < TS; ++sl) {
      const int s = st * TS + sl;
      float pq = pbuf[qo][s];
      float ws = wsum[s];
      float4 v0 = *(const float4*)&vt[sl][d0];
      float4 v1 = *(const float4*)&vt[sl][d0 + 4];
      float4 ke0 = *(const float4*)&kt[sl][e0];
      float4 ke1 = *(const float4*)&kt[sl][e0 + 4];
      float4 kd0 = *(const float4*)&kt[sl][d0];
      float4 kd1 = *(const float4*)&kt[sl][d0 + 4];
      float vv[8] = {v0.x, v0.y, v0.z, v0.w, v1.x, v1.y, v1.z, v1.w};
      float ke[8] = {ke0.x, ke0.y, ke0.z, ke0.w, ke1.x, ke1.y, ke1.z, ke1.w};
      float kd[8] = {kd0.x, kd0.y, kd0.z, kd0.w, kd1.x, kd1.y, kd1.z, kd1.w};
      float wv[8];
#pragma unroll
      for (int i = 0; i < 8; ++i) {
        outa[i] += pq * vv[i];
        kba[i] += pq * kd[i];
        wv[i] = ws * vv[i];
      }
#pragma unroll
      for (int i = 0; i < 8; ++i)
#pragma unroll
        for (int j = 0; j < 8; ++j) C[i][j] += wv[i] * ke[j];
    }
  }
  __syncthreads();  // all pbuf reads done -> safe to overlay

  // overlay out/kbar into dead score buffer
  float* out_d = &pbuf[0][0];
  float* kbar_d = out_d + 2048;
  float* out_c = out_d + 4096;
  float* kbar_c = out_d + 6144;
#pragma unroll
  for (int i = 0; i < 8; ++i) {
    out_d[qo * Dn + d0 + i] = outa[i];
    kbar_d[qo * Dn + d0 + i] = kba[i];
  }
  __syncthreads();

  // C -= sum_q out_q (x) kbar_q ; then scale+clip -> jac_dense
#pragma unroll
  for (int q = 0; q < Qn; ++q) {
    float4 o0 = *(const float4*)&out_d[q * Dn + d0];
    float4 o1 = *(const float4*)&out_d[q * Dn + d0 + 4];
    float4 k0 = *(const float4*)&kbar_d[q * Dn + e0];
    float4 k1 = *(const float4*)&kbar_d[q * Dn + e0 + 4];
    float od[8] = {o0.x, o0.y, o0.z, o0.w, o1.x, o1.y, o1.z, o1.w};
    float kb[8] = {k0.x, k0.y, k0.z, k0.w, k1.x, k1.y, k1.z, k1.w};
#pragma unroll
    for (int i = 0; i < 8; ++i)
#pragma unroll
      for (int j = 0; j < 8; ++j) C[i][j] -= od[i] * kb[j];
  }
#pragma unroll
  for (int i = 0; i < 8; ++i)
#pragma unroll
    for (int j = 0; j < 8; ++j)
      C[i][j] = fminf(fmaxf(SCALE * C[i][j], -CLIPV), CLIPV);

  // ---- CG path (M=8) ----
  if (t < Qn * Mn) {
    int q = t / Mn, sc = t % Mn;
    const float4* qrow = (const float4*)&qs[q][0];
    const float4* krow = (const float4*)(Kc + sc * Dn);
    float acc = 0.f;
#pragma unroll
    for (int kk = 0; kk < Dn / 4; ++kk) {
      float4 a = qrow[kk], c = krow[kk];
      acc += a.x * c.x + a.y * c.y + a.z * c.z + a.w * c.w;
    }
    pcg[q][sc] = acc * SCALE;
  }
  __syncthreads();
  if (t < Qn) {
    float m = -1e30f;
#pragma unroll
    for (int s = 0; s < Mn; ++s) m = fmaxf(m, pcg[t][s]);
    float sum = 0.f;
#pragma unroll
    for (int s = 0; s < Mn; ++s) {
      float e = expf(pcg[t][s] - m);
      pcg[t][s] = e;
      sum += e;
    }
    float inv = 1.f / sum;
#pragma unroll
    for (int s = 0; s < Mn; ++s) pcg[t][s] *= inv;
  }
  __syncthreads();
  if (t < Mn) {
    float w = 0.f;
#pragma unroll
    for (int q = 0; q < Qn; ++q) w += pcg[q][t];
    wcg[t] = w;
  }
  __syncthreads();

  float outc[8], kbc[8], C2[8][8];
#pragma unroll
  for (int i = 0; i < 8; ++i) {
    outc[i] = 0.f;
    kbc[i] = 0.f;
#pragma unroll
    for (int j = 0; j < 8; ++j) C2[i][j] = 0.f;
  }
#pragma unroll
  for (int s = 0; s < Mn; ++s) {
    float pq = pcg[qo][s];
    float ws = wcg[s];
    float4 v0 = *(const float4*)(Vc + s * Dn + d0);
    float4 v1 = *(const float4*)(Vc + s * Dn + d0 + 4);
    float4 ke0 = *(const float4*)(Kc + s * Dn + e0);
    float4 ke1 = *(const float4*)(Kc + s * Dn + e0 + 4);
    float4 kd0 = *(const float4*)(Kc + s * Dn + d0);
    float4 kd1 = *(const float4*)(Kc + s * Dn + d0 + 4);
    float vv[8] = {v0.x, v0.y, v0.z, v0.w, v1.x, v1.y, v1.z, v1.w};
    float ke[8] = {ke0.x, ke0.y, ke0.z, ke0.w, ke1.x, ke1.y, ke1.z, ke1.w};
    float kd[8] = {kd0.x, kd0.y, kd0.z, kd0.w, kd1.x, kd1.y, kd1.z, kd1.w};
    float wv[8];
#pragma unroll
    for (int i = 0; i < 8; ++i) {
      outc[i] += pq * vv[i];
      kbc[i] += pq * kd[i];
      wv[i] = ws * vv[i];
    }
#pragma unroll
    for (int i = 0; i < 8; ++i)
#pragma unroll
      for (int j = 0; j < 8; ++j) C2[i][j] += wv[i] * ke[j];
  }
#pragma unroll
  for (int i = 0; i < 8; ++i) {
    out_c[qo * Dn + d0 + i] = outc[i];
    kbar_c[qo * Dn + d0 + i] = kbc[i];
  }
  __syncthreads();
#pragma unroll
  for (int q = 0; q < Qn; ++q) {
    float4 o0 = *(const float4*)&out_c[q * Dn + d0];
    float4 o1 = *(const float4*)&out_c[q * Dn + d0 + 4];
    float4 k0 = *(const float4*)&kbar_c[q * Dn + e0];
    float4 k1 = *(const float4*)&kbar_c[q * Dn + e0 + 4];
    float od[8] = {o0.x, o0.y, o0.z, o0.w, o1.x, o1.y, o1.z, o1.w};
    float kb[8] = {k0.x, k0.y, k0.z, k0.w, k1.x, k1.y, k1.z, k1.w};
#pragma unroll
    for (int i = 0; i < 8; ++i)
#pragma unroll
      for (int j = 0; j < 8; ++j) C2[i][j] -= od[i] * kb[j];
  }
#pragma unroll
  for (int i = 0; i < 8; ++i)
#pragma unroll
    for (int j = 0; j < 8; ++j)
      C2[i][j] = fminf(fmaxf(SCALE * C2[i][j], -CLIPV), CLIPV);

  // ---- loss: cosine(jac_d, jac_c) + consistency ----
  float dot = 0.f, nd2 = 0.f, nc2 = 0.f;
#pragma unroll
  for (int i = 0; i < 8; ++i)
#pragma unroll
    for (int j = 0; j < 8; ++j) {
      dot += C[i][j] * C2[i][j];
      nd2 += C[i][j] * C[i][j];
      nc2 += C2[i][j] * C2[i][j];
    }
  float cons = 0.f;
#pragma unroll
  for (int i = 0; i < 8; ++i) {
    float df = out_d[qo * Dn + d0 + i] - out_c[qo * Dn + d0 + i];
    cons += df * df;
  }
#pragma unroll
  for (int o = 32; o; o >>= 1) {
    dot += __shfl_xor(dot, o);
    nd2 += __shfl_xor(nd2, o);
    nc2 += __shfl_xor(nc2, o);
    cons += __shfl_xor(cons, o);
  }
  if (lane == 0) {
    red[wave][0] = dot;
    red[wave][1] = nd2;
    red[wave][2] = nc2;
    red[wave][3] = cons;
  }
  __syncthreads();
  if (t == 0) {
    float d_ = 0.f, n1 = 0.f, n2 = 0.f, cs = 0.f;
#pragma unroll
    for (int w = 0; w < 4; ++w) {
      d_ += red[w][0];
      n1 += red[w][1];
      n2 += red[w][2];
      cs += red[w][3];
    }
    float cosv = d_ / (sqrtf(n1) * sqrtf(n2) + 1e-8f);
    float lb = (1.0f - cosv) + cs / (float)(Qn * Dn);
    atomicAdd(out, lb * (1.0f / (float)Bn));
  }
}
}  // namespace

extern "C" void kernel_launch(void* const* d_in, const int* in_sizes, int n_in,
                              void* d_out, int out_size, void* d_ws, size_t ws_size,
                              hipStream_t stream) {
  const float* q = (const float*)d_in[0];
  const float* k = (const float*)d_in[1];
  const float* v = (const float*)d_in[2];
  const float* kc = (const float*)d_in[3];
  const float* vc = (const float*)d_in[4];
  float* out = (float*)d_out;
  zero_kernel<<<1, 64, 0, stream>>>(out);
  fm_kernel<<<Bn, NT, 0, stream>>>(q, k, v, kc, vc, out);
}

// Round 2
// 171.197 us; speedup vs baseline: 1.9833x; 1.9833x over previous
//
#include <hip/hip_runtime.h>
#include <math.h>

// ForceMatchingLoss — MFMA bf16 rewrite. One block (512 thr, 8 waves) per batch.
// agg_jac = SCALE * ( V^T diag(w) K  -  Out^T Kbar ),  w_s = sum_q p_qs.
// The rank-16 subtraction runs as one extra pseudo k-step of the main GEMM.
// All MFMA use the guide-verified 16x16x32 bf16 fragment layouts.

namespace {
constexpr int Bn = 256, Qn = 16, Sn = 512, Mn = 8, Dn = 128;
constexpr int NT = 512;
constexpr float SCALE = 0.08838834764831845f;  // 1/sqrt(128)
constexpr float CLIPV = 50.0f;

// LDS byte offsets (single 16-aligned char arena)
constexpr int PB   = 0;       // bf16 [16][520]: scores -> probs (stride 1040 B)
constexpr int KT   = 16640;   // bf16 [128][34] K^T tile (pass2) | [64][136] K tile (pass1 spans KT..KT+17408)
constexpr int VT   = 25344;   // bf16 [128][34] V^T tile
constexpr int VTW  = 34048;   // bf16 [128][34] (w*V)^T tile
constexpr int WOFF = 42752;   // f32 [512] column sums w_s
constexpr int QS   = 44800;   // bf16 [16][136] scaled Q
constexpr int SCb  = 49152;   // f32 [16][16] cg scores
constexpr int PCG  = 50176;   // bf16 [16][34] cg probs (zero-padded k)
constexpr int WC   = 51264;   // f32 [8]
constexpr int RED  = 51328;   // f32 [8][4]
constexpr int LDSZ = 51456;

typedef __attribute__((ext_vector_type(8))) short bf16x8;
typedef __attribute__((ext_vector_type(4))) float f32x4;
#define MFMA16(a, b, c) __builtin_amdgcn_mfma_f32_16x16x32_bf16((a), (b), (c), 0, 0, 0)

__device__ inline unsigned short f2bf(float x) {
  unsigned int u = __builtin_bit_cast(unsigned int, x);
  u += 0x7fffu + ((u >> 16) & 1u);
  return (unsigned short)(u >> 16);
}
__device__ inline float bf2f(unsigned short h) {
  unsigned int u = ((unsigned int)h) << 16;
  return __builtin_bit_cast(float, u);
}
__device__ inline unsigned int pack2(float a, float b) {
  return (unsigned int)f2bf(a) | ((unsigned int)f2bf(b) << 16);
}
union Frag {
  bf16x8 v;
  unsigned int u[4];
  unsigned short h[8];
};
__device__ inline bf16x8 lds4x32(const char* p) {  // 4B-aligned 16B gather
  Frag f;
  f.u[0] = *(const unsigned int*)(p);
  f.u[1] = *(const unsigned int*)(p + 4);
  f.u[2] = *(const unsigned int*)(p + 8);
  f.u[3] = *(const unsigned int*)(p + 12);
  return f.v;
}

__device__ inline void c_kstep(const char* L, int r0, int c0, int l16, int quad,
                               f32x4 C0[4], f32x4 C1[4]) {
  bf16x8 A0 = lds4x32(L + VTW + (r0 + l16) * 68 + quad * 16);
  bf16x8 A1 = lds4x32(L + VTW + (r0 + 16 + l16) * 68 + quad * 16);
#pragma unroll
  for (int j = 0; j < 4; ++j) {
    bf16x8 Bj = lds4x32(L + KT + (c0 + 16 * j + l16) * 68 + quad * 16);
    C0[j] = MFMA16(A0, Bj, C0[j]);
    C1[j] = MFMA16(A1, Bj, C1[j]);
  }
}

__global__ void zero_kernel(float* out) {
  if (threadIdx.x == 0) out[0] = 0.0f;
}

__global__ __launch_bounds__(NT, 2) void fm_kernel(
    const float* __restrict__ Qg, const float* __restrict__ Kg,
    const float* __restrict__ Vg, const float* __restrict__ Kcg,
    const float* __restrict__ Vcg, float* __restrict__ out) {
  __shared__ __align__(16) char L[LDSZ];
  const int b = blockIdx.x;
  const int t = threadIdx.x;
  const int lane = t & 63, wave = t >> 6;
  const int quad = lane >> 4, l16 = lane & 15;

  const float* Qb = Qg + (size_t)b * Qn * Dn;
  const float* Kb = Kg + (size_t)b * Sn * Dn;
  const float* Vb = Vg + (size_t)b * Sn * Dn;
  const float* Kc = Kcg + (size_t)b * Mn * Dn;
  const float* Vc = Vcg + (size_t)b * Mn * Dn;

  // ---- Phase 0: Q (pre-scaled) -> Qs bf16 ----
  {
    int row = t >> 5, c4 = t & 31;
    float4 qv = ((const float4*)Qb)[t];
    unsigned long long pk = (unsigned long long)pack2(qv.x * SCALE, qv.y * SCALE) |
                            ((unsigned long long)pack2(qv.z * SCALE, qv.w * SCALE) << 32);
    *(unsigned long long*)(L + QS + row * 272 + c4 * 8) = pk;
  }

  // ---- Pass 1: scores S = (sQ)·K^T -> Pb (bf16), s-tiles of 64 ----
  bf16x8 aq[4];
  const bool score_wave = (wave < 4);
  float4 pf[4];
#pragma unroll
  for (int i = 0; i < 4; ++i) pf[i] = ((const float4*)Kb)[t + NT * i];
  for (int st = 0; st < 8; ++st) {
    __syncthreads();
#pragma unroll
    for (int i = 0; i < 4; ++i) {
      int g = t + NT * i;
      int row = g >> 5, c4 = g & 31;
      unsigned long long pk = (unsigned long long)pack2(pf[i].x, pf[i].y) |
                              ((unsigned long long)pack2(pf[i].z, pf[i].w) << 32);
      *(unsigned long long*)(L + KT + row * 272 + c4 * 8) = pk;
    }
    __syncthreads();
    if (st < 7) {
      const float4* nxt = (const float4*)(Kb + (size_t)(st + 1) * 64 * Dn);
#pragma unroll
      for (int i = 0; i < 4; ++i) pf[i] = nxt[t + NT * i];
    }
    if (st == 0 && score_wave) {
#pragma unroll
      for (int kk = 0; kk < 4; ++kk)
        aq[kk] = *(const bf16x8*)(L + QS + l16 * 272 + kk * 64 + quad * 16);
    }
    if (score_wave) {
      f32x4 acc = {0.f, 0.f, 0.f, 0.f};
#pragma unroll
      for (int kk = 0; kk < 4; ++kk) {
        bf16x8 bk = *(const bf16x8*)(L + KT + (wave * 16 + l16) * 272 + kk * 64 + quad * 16);
        acc = MFMA16(aq[kk], bk, acc);
      }
      int s = st * 64 + wave * 16 + l16;
#pragma unroll
      for (int r = 0; r < 4; ++r)
        *(unsigned short*)(L + PB + (quad * 4 + r) * 1040 + s * 2) = f2bf(acc[r]);
    }
  }
  __syncthreads();

  // ---- Softmax (bf16 rows, fp32 math): wave w owns rows 2w, 2w+1 ----
#pragma unroll
  for (int rr = 0; rr < 2; ++rr) {
    int q = wave * 2 + rr;
    char* rowp = L + PB + q * 1040;
    Frag f;
    f.v = *(const bf16x8*)(rowp + lane * 16);
    float x[8];
    float m = -1e30f;
#pragma unroll
    for (int j = 0; j < 8; ++j) { x[j] = bf2f(f.h[j]); m = fmaxf(m, x[j]); }
#pragma unroll
    for (int o = 32; o; o >>= 1) m = fmaxf(m, __shfl_xor(m, o));
    float ssum = 0.f;
#pragma unroll
    for (int j = 0; j < 8; ++j) { x[j] = __expf(x[j] - m); ssum += x[j]; }
#pragma unroll
    for (int o = 32; o; o >>= 1) ssum += __shfl_xor(ssum, o);
    float inv = 1.f / ssum;
    Frag g2;
#pragma unroll
    for (int j = 0; j < 8; ++j) g2.h[j] = f2bf(x[j] * inv);
    *(bf16x8*)(rowp + lane * 16) = g2.v;
  }
  __syncthreads();
  {  // w_s = sum_q p_qs
    float wsv = 0.f;
#pragma unroll
    for (int q = 0; q < Qn; ++q)
      wsv += bf2f(*(const unsigned short*)(L + PB + q * 1040 + t * 2));
    *(float*)(L + WOFF + t * 4) = wsv;
  }
  __syncthreads();

  // ---- Pass 2: out, kbar, C over s-tiles of 32 (transposed staging) ----
  f32x4 C0[4], C1[4];
  f32x4 outacc = {0.f, 0.f, 0.f, 0.f}, kbacc = {0.f, 0.f, 0.f, 0.f};
#pragma unroll
  for (int j = 0; j < 4; ++j) { C0[j] = (f32x4){0.f, 0.f, 0.f, 0.f}; C1[j] = (f32x4){0.f, 0.f, 0.f, 0.f}; }
  const int rp = wave & 3, ch = wave >> 2;
  const int r0 = rp * 32, c0 = ch * 64;
  const int dq = t & 31, s2 = t >> 5;

  float4 k0 = ((const float4*)(Kb + (size_t)(2 * s2) * Dn))[dq];
  float4 k1 = ((const float4*)(Kb + (size_t)(2 * s2 + 1) * Dn))[dq];
  float4 v0 = ((const float4*)(Vb + (size_t)(2 * s2) * Dn))[dq];
  float4 v1 = ((const float4*)(Vb + (size_t)(2 * s2 + 1) * Dn))[dq];

  for (int st = 0; st < 16; ++st) {
    __syncthreads();
    {
      float w0 = *(const float*)(L + WOFF + (st * 32 + 2 * s2) * 4);
      float w1 = *(const float*)(L + WOFF + (st * 32 + 2 * s2 + 1) * 4);
      float ka[4] = {k0.x, k0.y, k0.z, k0.w}, kb2[4] = {k1.x, k1.y, k1.z, k1.w};
      float va[4] = {v0.x, v0.y, v0.z, v0.w}, vb2[4] = {v1.x, v1.y, v1.z, v1.w};
#pragma unroll
      for (int j = 0; j < 4; ++j) {
        int d = dq * 4 + j;
        *(unsigned int*)(L + KT + d * 68 + s2 * 4) = pack2(ka[j], kb2[j]);
        *(unsigned int*)(L + VT + d * 68 + s2 * 4) = pack2(va[j], vb2[j]);
        *(unsigned int*)(L + VTW + d * 68 + s2 * 4) = pack2(w0 * va[j], w1 * vb2[j]);
      }
    }
    __syncthreads();
    if (st < 15) {
      int srow = (st + 1) * 32 + 2 * s2;
      k0 = ((const float4*)(Kb + (size_t)srow * Dn))[dq];
      k1 = ((const float4*)(Kb + (size_t)(srow + 1) * Dn))[dq];
      v0 = ((const float4*)(Vb + (size_t)srow * Dn))[dq];
      v1 = ((const float4*)(Vb + (size_t)(srow + 1) * Dn))[dq];
    }
    {  // out/kbar: wave owns d-col-tile `wave`
      bf16x8 pA = *(const bf16x8*)(L + PB + l16 * 1040 + (st * 32 + quad * 8) * 2);
      bf16x8 bV = lds4x32(L + VT + (wave * 16 + l16) * 68 + quad * 16);
      bf16x8 bK = lds4x32(L + KT + (wave * 16 + l16) * 68 + quad * 16);
      outacc = MFMA16(pA, bV, outacc);
      kbacc = MFMA16(pA, bK, kbacc);
    }
    c_kstep(L, r0, c0, l16, quad, C0, C1);
  }
  __syncthreads();

  // ---- Dense pseudo k-step: C -= Out^T · Kbar ----
#pragma unroll
  for (int r = 0; r < 4; ++r) {
    int d = wave * 16 + l16, q = quad * 4 + r;
    *(unsigned short*)(L + VTW + d * 68 + q * 2) = f2bf(-outacc[r]);
    *(unsigned short*)(L + KT + d * 68 + q * 2) = f2bf(kbacc[r]);
  }
  {
    int d = t & 127, part = t >> 7;
#pragma unroll
    for (int z = 0; z < 2; ++z) {
      int s2z = 8 + part * 2 + z;
      *(unsigned int*)(L + KT + d * 68 + s2z * 4) = 0u;
      *(unsigned int*)(L + VTW + d * 68 + s2z * 4) = 0u;
    }
  }
  __syncthreads();
  c_kstep(L, r0, c0, l16, quad, C0, C1);
#pragma unroll
  for (int j = 0; j < 4; ++j)
#pragma unroll
    for (int r = 0; r < 4; ++r) {
      C0[j][r] = fminf(fmaxf(SCALE * C0[j][r], -CLIPV), CLIPV);
      C1[j][r] = fminf(fmaxf(SCALE * C1[j][r], -CLIPV), CLIPV);
    }

  // ---- CG path (M=8) ----
  __syncthreads();
  if (t < 256) {  // stage Kc as [8][136] bf16 at KT
    int row = t >> 5, c4 = t & 31;
    float4 kv = ((const float4*)Kc)[t];
    unsigned long long pk = (unsigned long long)pack2(kv.x, kv.y) |
                            ((unsigned long long)pack2(kv.z, kv.w) << 32);
    *(unsigned long long*)(L + KT + row * 272 + c4 * 8) = pk;
  }
  __syncthreads();
  if (wave == 0) {  // cg scores (cols 8..15 garbage, ignored)
    f32x4 acc = {0.f, 0.f, 0.f, 0.f};
#pragma unroll
    for (int kk = 0; kk < 4; ++kk) {
      bf16x8 a = *(const bf16x8*)(L + QS + l16 * 272 + kk * 64 + quad * 16);
      bf16x8 bk = *(const bf16x8*)(L + KT + (l16 & 7) * 272 + kk * 64 + quad * 16);
      acc = MFMA16(a, bk, acc);
    }
#pragma unroll
    for (int r = 0; r < 4; ++r)
      *(float*)(L + SCb + (quad * 4 + r) * 64 + l16 * 4) = acc[r];
  }
  __syncthreads();
  if (t < 16) {  // cg softmax row t
    float xs[8];
    float m = -1e30f;
#pragma unroll
    for (int s = 0; s < 8; ++s) { xs[s] = *(const float*)(L + SCb + t * 64 + s * 4); m = fmaxf(m, xs[s]); }
    float ssum = 0.f;
#pragma unroll
    for (int s = 0; s < 8; ++s) { xs[s] = __expf(xs[s] - m); ssum += xs[s]; }
    float inv = 1.f / ssum;
#pragma unroll
    for (int s = 0; s < 8; ++s) *(unsigned short*)(L + PCG + t * 68 + s * 2) = f2bf(xs[s] * inv);
#pragma unroll
    for (int s = 8; s < 32; ++s) *(unsigned short*)(L + PCG + t * 68 + s * 2) = 0;
  }
  __syncthreads();
  if (t < 8) {
    float wsv = 0.f;
#pragma unroll
    for (int q = 0; q < 16; ++q)
      wsv += bf2f(*(const unsigned short*)(L + PCG + q * 68 + t * 2));
    *(float*)(L + WC + t * 4) = wsv;
  }
  __syncthreads();
  {  // stage Kct/Vct/Vcwt transposed, zero-padded to 32 cols
    int d = t & 127, grp = t >> 7;
    float kc0 = Kc[(size_t)(2 * grp) * Dn + d], kc1 = Kc[(size_t)(2 * grp + 1) * Dn + d];
    float vc0 = Vc[(size_t)(2 * grp) * Dn + d], vc1 = Vc[(size_t)(2 * grp + 1) * Dn + d];
    float wc0 = *(const float*)(L + WC + (2 * grp) * 4);
    float wc1 = *(const float*)(L + WC + (2 * grp + 1) * 4);
    *(unsigned int*)(L + KT + d * 68 + grp * 4) = pack2(kc0, kc1);
    *(unsigned int*)(L + VT + d * 68 + grp * 4) = pack2(vc0, vc1);
    *(unsigned int*)(L + VTW + d * 68 + grp * 4) = pack2(wc0 * vc0, wc1 * vc1);
#pragma unroll
    for (int z = 0; z < 3; ++z) {
      int s2z = 4 + grp * 3 + z;
      *(unsigned int*)(L + KT + d * 68 + s2z * 4) = 0u;
      *(unsigned int*)(L + VT + d * 68 + s2z * 4) = 0u;
      *(unsigned int*)(L + VTW + d * 68 + s2z * 4) = 0u;
    }
  }
  __syncthreads();
  f32x4 outc = {0.f, 0.f, 0.f, 0.f}, kbc = {0.f, 0.f, 0.f, 0.f};
  {
    bf16x8 pA = lds4x32(L + PCG + l16 * 68 + quad * 16);
    bf16x8 bV = lds4x32(L + VT + (wave * 16 + l16) * 68 + quad * 16);
    bf16x8 bK = lds4x32(L + KT + (wave * 16 + l16) * 68 + quad * 16);
    outc = MFMA16(pA, bV, outc);
    kbc = MFMA16(pA, bK, kbc);
  }
  f32x4 D0[4], D1[4];
#pragma unroll
  for (int j = 0; j < 4; ++j) { D0[j] = (f32x4){0.f, 0.f, 0.f, 0.f}; D1[j] = (f32x4){0.f, 0.f, 0.f, 0.f}; }
  c_kstep(L, r0, c0, l16, quad, D0, D1);
  __syncthreads();
#pragma unroll
  for (int r = 0; r < 4; ++r) {
    int d = wave * 16 + l16, q = quad * 4 + r;
    *(unsigned short*)(L + VTW + d * 68 + q * 2) = f2bf(-outc[r]);
    *(unsigned short*)(L + KT + d * 68 + q * 2) = f2bf(kbc[r]);
  }
  {
    int d = t & 127, part = t >> 7;
#pragma unroll
    for (int z = 0; z < 2; ++z) {
      int s2z = 8 + part * 2 + z;
      *(unsigned int*)(L + KT + d * 68 + s2z * 4) = 0u;
      *(unsigned int*)(L + VTW + d * 68 + s2z * 4) = 0u;
    }
  }
  __syncthreads();
  c_kstep(L, r0, c0, l16, quad, D0, D1);
#pragma unroll
  for (int j = 0; j < 4; ++j)
#pragma unroll
    for (int r = 0; r < 4; ++r) {
      D0[j][r] = fminf(fmaxf(SCALE * D0[j][r], -CLIPV), CLIPV);
      D1[j][r] = fminf(fmaxf(SCALE * D1[j][r], -CLIPV), CLIPV);
    }

  // ---- Loss ----
  float dot = 0.f, nd2 = 0.f, nc2 = 0.f, cons = 0.f;
#pragma unroll
  for (int j = 0; j < 4; ++j)
#pragma unroll
    for (int r = 0; r < 4; ++r) {
      dot += C0[j][r] * D0[j][r] + C1[j][r] * D1[j][r];
      nd2 += C0[j][r] * C0[j][r] + C1[j][r] * C1[j][r];
      nc2 += D0[j][r] * D0[j][r] + D1[j][r] * D1[j][r];
    }
#pragma unroll
  for (int r = 0; r < 4; ++r) {
    float df = outacc[r] - outc[r];
    cons += df * df;
  }
#pragma unroll
  for (int o = 32; o; o >>= 1) {
    dot += __shfl_xor(dot, o);
    nd2 += __shfl_xor(nd2, o);
    nc2 += __shfl_xor(nc2, o);
    cons += __shfl_xor(cons, o);
  }
  if (lane == 0) {
    float* red = (float*)(L + RED);
    red[wave * 4 + 0] = dot;
    red[wave * 4 + 1] = nd2;
    red[wave * 4 + 2] = nc2;
    red[wave * 4 + 3] = cons;
  }
  __syncthreads();
  if (t == 0) {
    const float* red = (const float*)(L + RED);
    float d_ = 0.f, n1 = 0.f, n2 = 0.f, cs = 0.f;
#pragma unroll
    for (int w = 0; w < 8; ++w) {
      d_ += red[w * 4 + 0];
      n1 += red[w * 4 + 1];
      n2 += red[w * 4 + 2];
      cs += red[w * 4 + 3];
    }
    float cosv = d_ / (sqrtf(n1) * sqrtf(n2) + 1e-8f);
    float lb = (1.0f - cosv) + cs / (float)(Qn * Dn);
    atomicAdd(out, lb * (1.0f / (float)Bn));
  }
}
}  // namespace

extern "C" void kernel_launch(void* const* d_in, const int* in_sizes, int n_in,
                              void* d_out, int out_size, void* d_ws, size_t ws_size,
                              hipStream_t stream) {
  const float* q = (const float*)d_in[0];
  const float* k = (const float*)d_in[1];
  const float* v = (const float*)d_in[2];
  const float* kc = (const float*)d_in[3];
  const float* vc = (const float*)d_in[4];
  float* out = (float*)d_out;
  zero_kernel<<<1, 64, 0, stream>>>(out);
  fm_kernel<<<Bn, NT, 0, stream>>>(q, k, v, kc, vc, out);
}

// Round 3
// 168.962 us; speedup vs baseline: 2.0095x; 1.0132x over previous
//
#include <hip/hip_runtime.h>
#include <math.h>

// ForceMatchingLoss — R3: 2 blocks/batch (grid 512), conflict-free transposed
// staging (ds_write_b128, stride 144B), pass1 scores direct-from-global (no
// barriers), perm-packed bf16 conversion. Loss partials combined via ws +
// finalize kernel.
// agg_jac = SCALE * ( V^T diag(w) K - Out^T Kbar ), w_s = sum_q p_qs.
// Block h of pair handles V-dim rows [64h, 64h+64) of C and out; kbar full.

namespace {
constexpr int Bn = 256, Qn = 16, Sn = 512, Mn = 8, Dn = 128;
constexpr int NT = 512;
constexpr float SCALE = 0.08838834764831845f;  // 1/sqrt(128)
constexpr float CLIPV = 50.0f;

// LDS layout (bytes)
constexpr int QS    = 0;            // bf16 [16][136] stride 272  -> 4352
constexpr int PB    = 4352;         // bf16 [16][520] stride 1040 -> 16640
constexpr int WOFF  = 20992;        // f32 [512]                  -> 2048
constexpr int ARENA = 23040;        // 36864 (SCF aliases KT/VT/VTW)
constexpr int KT    = ARENA;        // bf16 [128][72] stride 144  -> 18432
constexpr int VT    = ARENA + 18432; // bf16 [64][72]             -> 9216
constexpr int VTW   = ARENA + 27648; // bf16 [64][72]             -> 9216
constexpr int SCF   = ARENA;        // f32 [16][516] stride 2064  -> 33024
constexpr int CGS   = 59904;        // f32 [16][8] stride 32      -> 512
constexpr int PCG   = 60416;        // bf16 [16][40] stride 80    -> 1280
constexpr int WC    = 61696;        // f32 [8]                    -> 32
constexpr int RED   = 61728;        // f32 [8][4]                 -> 128
constexpr int LDSZ  = 61856;        // < 64KB static; 2 blocks = 124KB < 160KB

typedef __attribute__((ext_vector_type(8))) short bf16x8;
typedef __attribute__((ext_vector_type(4))) float f32x4;
#define MFMA16(a, b, c) __builtin_amdgcn_mfma_f32_16x16x32_bf16((a), (b), (c), 0, 0, 0)

// truncating fp32->bf16 pair pack: 1 v_perm_b32
__device__ inline unsigned int pack2t(float a, float b) {
  return __builtin_amdgcn_perm(__builtin_bit_cast(unsigned int, b),
                               __builtin_bit_cast(unsigned int, a), 0x07060302u);
}
__device__ inline unsigned short f2bf(float x) {  // RNE (cold paths)
  unsigned int u = __builtin_bit_cast(unsigned int, x);
  u += 0x7fffu + ((u >> 16) & 1u);
  return (unsigned short)(u >> 16);
}
__device__ inline float bf2f(unsigned short h) {
  unsigned int u = ((unsigned int)h) << 16;
  return __builtin_bit_cast(float, u);
}
union Frag {
  bf16x8 v;
  unsigned int u[4];
  unsigned short h[8];
};

__global__ void zero_ws_kernel(float4* ws) {
  ws[threadIdx.x] = make_float4(0.f, 0.f, 0.f, 0.f);  // 256 thr * 4 = 1024 f32
}

__global__ void finalize_kernel(const float* __restrict__ ws, float* __restrict__ out) {
  __shared__ float sr[256];
  int i = threadIdx.x;
  float dt = ws[i * 4 + 0], n1 = ws[i * 4 + 1], n2 = ws[i * 4 + 2], cs = ws[i * 4 + 3];
  float cosv = dt / (sqrtf(n1) * sqrtf(n2) + 1e-8f);
  sr[i] = (1.0f - cosv) + cs * (1.0f / (float)(Qn * Dn));
  __syncthreads();
  for (int off = 128; off; off >>= 1) {
    if (i < off) sr[i] += sr[i + off];
    __syncthreads();
  }
  if (i == 0) out[0] = sr[0] * (1.0f / (float)Bn);
}

__global__ __launch_bounds__(NT, 4) void fm_kernel(
    const float* __restrict__ Qg, const float* __restrict__ Kg,
    const float* __restrict__ Vg, const float* __restrict__ Kcg,
    const float* __restrict__ Vcg, float* __restrict__ ws) {
  __shared__ __align__(16) char L[LDSZ];
  const int bid = blockIdx.x, b = bid >> 1, h = bid & 1;
  const int t = threadIdx.x, lane = t & 63, wv = t >> 6;
  const int quad = lane >> 4, l16 = lane & 15;

  const float* Qb = Qg + (size_t)b * Qn * Dn;
  const float* Kb = Kg + (size_t)b * Sn * Dn;
  const float* Vb = Vg + (size_t)b * Sn * Dn;
  const float* Kc = Kcg + (size_t)b * Mn * Dn;
  const float* Vc = Vcg + (size_t)b * Mn * Dn;

  // staging roles (pass 2): thread owns 8 consecutive s for one dim
  const int dK = t & 127, gK = t >> 7;  // K: octets gK, gK+4 of 8
  const int dV = t & 63, gV = t >> 6;   // V: octet gV (==wave, uniform)
  float kpf[2][8], vpf[8];

  auto load_tiles = [&](int st) {
#pragma unroll
    for (int o = 0; o < 2; ++o) {
      int s0 = st * 64 + (gK + 4 * o) * 8;
#pragma unroll
      for (int i = 0; i < 8; ++i) kpf[o][i] = Kb[(size_t)(s0 + i) * Dn + dK];
    }
    int s1 = st * 64 + gV * 8;
#pragma unroll
    for (int i = 0; i < 8; ++i) vpf[i] = Vb[(size_t)(s1 + i) * Dn + h * 64 + dV];
  };
  auto store_tiles = [&](int st) {
#pragma unroll
    for (int o = 0; o < 2; ++o) {
      unsigned int u0 = pack2t(kpf[o][0], kpf[o][1]), u1 = pack2t(kpf[o][2], kpf[o][3]);
      unsigned int u2 = pack2t(kpf[o][4], kpf[o][5]), u3 = pack2t(kpf[o][6], kpf[o][7]);
      *(uint4*)(L + KT + dK * 144 + (gK + 4 * o) * 16) = make_uint4(u0, u1, u2, u3);
    }
    int s1 = st * 64 + gV * 8;
    float wv8[8];
#pragma unroll
    for (int i = 0; i < 8; ++i) wv8[i] = *(const float*)(L + WOFF + (s1 + i) * 4);
    unsigned int v0 = pack2t(vpf[0], vpf[1]), v1 = pack2t(vpf[2], vpf[3]);
    unsigned int v2 = pack2t(vpf[4], vpf[5]), v3 = pack2t(vpf[6], vpf[7]);
    *(uint4*)(L + VT + dV * 144 + gV * 16) = make_uint4(v0, v1, v2, v3);
    unsigned int w0 = pack2t(wv8[0] * vpf[0], wv8[1] * vpf[1]);
    unsigned int w1 = pack2t(wv8[2] * vpf[2], wv8[3] * vpf[3]);
    unsigned int w2 = pack2t(wv8[4] * vpf[4], wv8[5] * vpf[5]);
    unsigned int w3 = pack2t(wv8[6] * vpf[6], wv8[7] * vpf[7]);
    *(uint4*)(L + VTW + dV * 144 + gV * 16) = make_uint4(w0, w1, w2, w3);
  };

  // ---- Q (pre-scaled) -> QS bf16 ----
  {
    int row = t >> 5, c4 = t & 31;
    float4 qv = ((const float4*)Qb)[t];
    unsigned int p0 = pack2t(qv.x * SCALE, qv.y * SCALE);
    unsigned int p1 = pack2t(qv.z * SCALE, qv.w * SCALE);
    *(unsigned long long*)(L + QS + row * 272 + c4 * 8) =
        (unsigned long long)p0 | ((unsigned long long)p1 << 32);
  }
  load_tiles(0);  // deep prefetch for pass2 tile 0
  __syncthreads();

  // ---- Pass 1: scores, each wave an independent 16x64 strip (no barriers) ----
  {
    bf16x8 aq[4];
#pragma unroll
    for (int kk = 0; kk < 4; ++kk)
      aq[kk] = *(const bf16x8*)(L + QS + l16 * 272 + kk * 64 + quad * 16);
    for (int j = 0; j < 4; ++j) {
      int srow = 64 * wv + 16 * j + l16;
      const float* kp = Kb + (size_t)srow * Dn + quad * 8;
      f32x4 acc = {0.f, 0.f, 0.f, 0.f};
#pragma unroll
      for (int kk = 0; kk < 4; ++kk) {
        float4 lo = *(const float4*)(kp + kk * 32);
        float4 hi = *(const float4*)(kp + kk * 32 + 4);
        Frag f;
        f.u[0] = pack2t(lo.x, lo.y);
        f.u[1] = pack2t(lo.z, lo.w);
        f.u[2] = pack2t(hi.x, hi.y);
        f.u[3] = pack2t(hi.z, hi.w);
        acc = MFMA16(aq[kk], f.v, acc);
      }
      int s = 64 * wv + 16 * j + l16;
#pragma unroll
      for (int r = 0; r < 4; ++r)
        *(float*)(L + SCF + (quad * 4 + r) * 2064 + s * 4) = acc[r];
    }
  }
  __syncthreads();

  // ---- Softmax: wave wv owns rows 2wv, 2wv+1; write bf16 probs -> PB ----
#pragma unroll
  for (int rr = 0; rr < 2; ++rr) {
    int q = wv * 2 + rr;
    const float* srow = (const float*)(L + SCF + q * 2064);
    float x[8];
    float m = -1e30f;
#pragma unroll
    for (int i = 0; i < 8; ++i) { x[i] = srow[lane * 8 + i]; m = fmaxf(m, x[i]); }
#pragma unroll
    for (int o = 32; o; o >>= 1) m = fmaxf(m, __shfl_xor(m, o));
    float ssum = 0.f;
#pragma unroll
    for (int i = 0; i < 8; ++i) { x[i] = __expf(x[i] - m); ssum += x[i]; }
#pragma unroll
    for (int o = 32; o; o >>= 1) ssum += __shfl_xor(ssum, o);
    float inv = 1.f / ssum;
    Frag g;
#pragma unroll
    for (int i = 0; i < 8; ++i) g.h[i] = f2bf(x[i] * inv);
    *(bf16x8*)(L + PB + q * 1040 + lane * 16) = g.v;
  }
  __syncthreads();
  {  // w_s = sum_q p_qs
    float wsv = 0.f;
#pragma unroll
    for (int q = 0; q < Qn; ++q)
      wsv += bf2f(*(const unsigned short*)(L + PB + q * 1040 + t * 2));
    *(float*)(L + WOFF + t * 4) = wsv;
  }
  __syncthreads();

  // ---- Pass 2: 8 iterations of 64 s-rows ----
  const int rp = wv & 1, ch = wv >> 1;  // C tile: rows rp*32, cols ch*32 (local)
  f32x4 C00 = {0.f,0.f,0.f,0.f}, C01 = {0.f,0.f,0.f,0.f};
  f32x4 C10 = {0.f,0.f,0.f,0.f}, C11 = {0.f,0.f,0.f,0.f};
  f32x4 outacc = {0.f,0.f,0.f,0.f}, kbacc = {0.f,0.f,0.f,0.f};

  auto ckstep = [&](int colByte, f32x4& c00, f32x4& c01, f32x4& c10, f32x4& c11) {
    bf16x8 A0 = *(const bf16x8*)(L + VTW + (rp * 32 + l16) * 144 + colByte + quad * 16);
    bf16x8 A1 = *(const bf16x8*)(L + VTW + (rp * 32 + 16 + l16) * 144 + colByte + quad * 16);
    bf16x8 B0 = *(const bf16x8*)(L + KT + (ch * 32 + l16) * 144 + colByte + quad * 16);
    bf16x8 B1 = *(const bf16x8*)(L + KT + (ch * 32 + 16 + l16) * 144 + colByte + quad * 16);
    c00 = MFMA16(A0, B0, c00);
    c01 = MFMA16(A0, B1, c01);
    c10 = MFMA16(A1, B0, c10);
    c11 = MFMA16(A1, B1, c11);
  };

  for (int st = 0; st < 8; ++st) {
    if (st) __syncthreads();
    store_tiles(st);
    __syncthreads();
    if (st < 7) load_tiles(st + 1);
#pragma unroll
    for (int z = 0; z < 2; ++z) {
      int colByte = z * 64;
      bf16x8 pA = *(const bf16x8*)(L + PB + l16 * 1040 + st * 128 + z * 64 + quad * 16);
      bf16x8 bK = *(const bf16x8*)(L + KT + (wv * 16 + l16) * 144 + colByte + quad * 16);
      kbacc = MFMA16(pA, bK, kbacc);
      if (wv < 4) {
        bf16x8 bV = *(const bf16x8*)(L + VT + (wv * 16 + l16) * 144 + colByte + quad * 16);
        outacc = MFMA16(pA, bV, outacc);
      }
      ckstep(colByte, C00, C01, C10, C11);
    }
  }
  __syncthreads();

  // ---- Dense pseudo k-step: C -= Out^T · Kbar ----
  if (wv < 4) {
#pragma unroll
    for (int r = 0; r < 4; ++r)
      *(unsigned short*)(L + VTW + (wv * 16 + l16) * 144 + (quad * 4 + r) * 2) = f2bf(-outacc[r]);
  }
#pragma unroll
  for (int r = 0; r < 4; ++r)
    *(unsigned short*)(L + KT + (wv * 16 + l16) * 144 + (quad * 4 + r) * 2) = f2bf(kbacc[r]);
  if (t < 256) {
    *(uint4*)(L + KT + (t >> 1) * 144 + 32 + (t & 1) * 16) = make_uint4(0, 0, 0, 0);
  } else if (t < 384) {
    int i = t - 256;
    *(uint4*)(L + VTW + (i >> 1) * 144 + 32 + (i & 1) * 16) = make_uint4(0, 0, 0, 0);
  }
  __syncthreads();
  ckstep(0, C00, C01, C10, C11);
#pragma unroll
  for (int r = 0; r < 4; ++r) {
    C00[r] = fminf(fmaxf(SCALE * C00[r], -CLIPV), CLIPV);
    C01[r] = fminf(fmaxf(SCALE * C01[r], -CLIPV), CLIPV);
    C10[r] = fminf(fmaxf(SCALE * C10[r], -CLIPV), CLIPV);
    C11[r] = fminf(fmaxf(SCALE * C11[r], -CLIPV), CLIPV);
  }
  __syncthreads();  // arena free for CG

  // ---- CG scores (wave 0, direct from global) ----
  if (wv == 0) {
    f32x4 acc = {0.f, 0.f, 0.f, 0.f};
    const float* kp = Kc + (size_t)(l16 & 7) * Dn + quad * 8;
#pragma unroll
    for (int kk = 0; kk < 4; ++kk) {
      bf16x8 a = *(const bf16x8*)(L + QS + l16 * 272 + kk * 64 + quad * 16);
      float4 lo = *(const float4*)(kp + kk * 32);
      float4 hi = *(const float4*)(kp + kk * 32 + 4);
      Frag f;
      f.u[0] = pack2t(lo.x, lo.y);
      f.u[1] = pack2t(lo.z, lo.w);
      f.u[2] = pack2t(hi.x, hi.y);
      f.u[3] = pack2t(hi.z, hi.w);
      acc = MFMA16(a, f.v, acc);
    }
    if (l16 < 8) {
#pragma unroll
      for (int r = 0; r < 4; ++r)
        *(float*)(L + CGS + (quad * 4 + r) * 32 + l16 * 4) = acc[r];
    }
  }
  __syncthreads();
  if (t < 16) {  // cg softmax row t -> PCG (cols 8..31 zeroed)
    float xs[8];
    float m = -1e30f;
#pragma unroll
    for (int s = 0; s < 8; ++s) { xs[s] = *(const float*)(L + CGS + t * 32 + s * 4); m = fmaxf(m, xs[s]); }
    float ssum = 0.f;
#pragma unroll
    for (int s = 0; s < 8; ++s) { xs[s] = __expf(xs[s] - m); ssum += xs[s]; }
    float inv = 1.f / ssum;
#pragma unroll
    for (int s = 0; s < 4; ++s)
      *(unsigned int*)(L + PCG + t * 80 + s * 4) = pack2t(xs[2 * s] * inv, xs[2 * s + 1] * inv);
#pragma unroll
    for (int p = 4; p < 16; ++p) *(unsigned int*)(L + PCG + t * 80 + p * 4) = 0u;
  }
  __syncthreads();
  if (t < 8) {
    float s = 0.f;
#pragma unroll
    for (int q = 0; q < Qn; ++q) s += bf2f(*(const unsigned short*)(L + PCG + q * 80 + t * 2));
    *(float*)(L + WC + t * 4) = s;
  }
  __syncthreads();
  // ---- stage CG transposed (cols 8..31 zero) ----
  if (t < 128) {
    float kv[8];
#pragma unroll
    for (int i = 0; i < 8; ++i) kv[i] = Kc[(size_t)i * Dn + t];
    *(uint4*)(L + KT + t * 144) = make_uint4(pack2t(kv[0], kv[1]), pack2t(kv[2], kv[3]),
                                             pack2t(kv[4], kv[5]), pack2t(kv[6], kv[7]));
    *(uint4*)(L + KT + t * 144 + 16) = make_uint4(0, 0, 0, 0);
    *(uint4*)(L + KT + t * 144 + 32) = make_uint4(0, 0, 0, 0);
    *(uint4*)(L + KT + t * 144 + 48) = make_uint4(0, 0, 0, 0);
  } else if (t < 192) {
    int d = t - 128;
    float vv2[8];
#pragma unroll
    for (int i = 0; i < 8; ++i) vv2[i] = Vc[(size_t)i * Dn + h * 64 + d];
    *(uint4*)(L + VT + d * 144) = make_uint4(pack2t(vv2[0], vv2[1]), pack2t(vv2[2], vv2[3]),
                                             pack2t(vv2[4], vv2[5]), pack2t(vv2[6], vv2[7]));
    *(uint4*)(L + VT + d * 144 + 16) = make_uint4(0, 0, 0, 0);
    *(uint4*)(L + VT + d * 144 + 32) = make_uint4(0, 0, 0, 0);
    *(uint4*)(L + VT + d * 144 + 48) = make_uint4(0, 0, 0, 0);
  } else if (t < 256) {
    int d = t - 192;
    float vv2[8], wcv[8];
#pragma unroll
    for (int i = 0; i < 8; ++i) {
      vv2[i] = Vc[(size_t)i * Dn + h * 64 + d];
      wcv[i] = *(const float*)(L + WC + i * 4);
    }
    *(uint4*)(L + VTW + d * 144) =
        make_uint4(pack2t(wcv[0] * vv2[0], wcv[1] * vv2[1]), pack2t(wcv[2] * vv2[2], wcv[3] * vv2[3]),
                   pack2t(wcv[4] * vv2[4], wcv[5] * vv2[5]), pack2t(wcv[6] * vv2[6], wcv[7] * vv2[7]));
    *(uint4*)(L + VTW + d * 144 + 16) = make_uint4(0, 0, 0, 0);
    *(uint4*)(L + VTW + d * 144 + 32) = make_uint4(0, 0, 0, 0);
    *(uint4*)(L + VTW + d * 144 + 48) = make_uint4(0, 0, 0, 0);
  }
  __syncthreads();
  f32x4 outc = {0.f,0.f,0.f,0.f}, kbc = {0.f,0.f,0.f,0.f};
  f32x4 D00 = {0.f,0.f,0.f,0.f}, D01 = {0.f,0.f,0.f,0.f};
  f32x4 D10 = {0.f,0.f,0.f,0.f}, D11 = {0.f,0.f,0.f,0.f};
  {
    bf16x8 pA = *(const bf16x8*)(L + PCG + l16 * 80 + quad * 16);
    bf16x8 bK = *(const bf16x8*)(L + KT + (wv * 16 + l16) * 144 + quad * 16);
    kbc = MFMA16(pA, bK, kbc);
    if (wv < 4) {
      bf16x8 bV = *(const bf16x8*)(L + VT + (wv * 16 + l16) * 144 + quad * 16);
      outc = MFMA16(pA, bV, outc);
    }
    ckstep(0, D00, D01, D10, D11);
  }
  __syncthreads();
  // cg pseudo k-step (bytes 32..63 of rows are already zero from staging)
  if (wv < 4) {
#pragma unroll
    for (int r = 0; r < 4; ++r)
      *(unsigned short*)(L + VTW + (wv * 16 + l16) * 144 + (quad * 4 + r) * 2) = f2bf(-outc[r]);
  }
#pragma unroll
  for (int r = 0; r < 4; ++r)
    *(unsigned short*)(L + KT + (wv * 16 + l16) * 144 + (quad * 4 + r) * 2) = f2bf(kbc[r]);
  __syncthreads();
  ckstep(0, D00, D01, D10, D11);
#pragma unroll
  for (int r = 0; r < 4; ++r) {
    D00[r] = fminf(fmaxf(SCALE * D00[r], -CLIPV), CLIPV);
    D01[r] = fminf(fmaxf(SCALE * D01[r], -CLIPV), CLIPV);
    D10[r] = fminf(fmaxf(SCALE * D10[r], -CLIPV), CLIPV);
    D11[r] = fminf(fmaxf(SCALE * D11[r], -CLIPV), CLIPV);
  }

  // ---- Loss partials ----
  float dot = 0.f, nd2 = 0.f, nc2 = 0.f, cons = 0.f;
#pragma unroll
  for (int r = 0; r < 4; ++r) {
    dot += C00[r] * D00[r] + C01[r] * D01[r] + C10[r] * D10[r] + C11[r] * D11[r];
    nd2 += C00[r] * C00[r] + C01[r] * C01[r] + C10[r] * C10[r] + C11[r] * C11[r];
    nc2 += D00[r] * D00[r] + D01[r] * D01[r] + D10[r] * D10[r] + D11[r] * D11[r];
  }
  if (wv < 4) {
#pragma unroll
    for (int r = 0; r < 4; ++r) {
      float df = outacc[r] - outc[r];
      cons += df * df;
    }
  }
#pragma unroll
  for (int o = 32; o; o >>= 1) {
    dot += __shfl_xor(dot, o);
    nd2 += __shfl_xor(nd2, o);
    nc2 += __shfl_xor(nc2, o);
    cons += __shfl_xor(cons, o);
  }
  if (lane == 0) {
    float* red = (float*)(L + RED);
    red[wv * 4 + 0] = dot;
    red[wv * 4 + 1] = nd2;
    red[wv * 4 + 2] = nc2;
    red[wv * 4 + 3] = cons;
  }
  __syncthreads();
  if (t == 0) {
    const float* red = (const float*)(L + RED);
    float d_ = 0.f, n1 = 0.f, n2 = 0.f, cs = 0.f;
#pragma unroll
    for (int w = 0; w < 8; ++w) {
      d_ += red[w * 4 + 0];
      n1 += red[w * 4 + 1];
      n2 += red[w * 4 + 2];
      cs += red[w * 4 + 3];
    }
    atomicAdd(ws + b * 4 + 0, d_);
    atomicAdd(ws + b * 4 + 1, n1);
    atomicAdd(ws + b * 4 + 2, n2);
    atomicAdd(ws + b * 4 + 3, cs);
  }
}
}  // namespace

extern "C" void kernel_launch(void* const* d_in, const int* in_sizes, int n_in,
                              void* d_out, int out_size, void* d_ws, size_t ws_size,
                              hipStream_t stream) {
  const float* q = (const float*)d_in[0];
  const float* k = (const float*)d_in[1];
  const float* v = (const float*)d_in[2];
  const float* kc = (const float*)d_in[3];
  const float* vc = (const float*)d_in[4];
  float* out = (float*)d_out;
  float* ws = (float*)d_ws;
  zero_ws_kernel<<<1, 256, 0, stream>>>((float4*)ws);
  fm_kernel<<<2 * Bn, NT, 0, stream>>>(q, k, v, kc, vc, ws);
  finalize_kernel<<<1, 256, 0, stream>>>(ws, out);
}